// Round 9
// baseline (18.101 us; speedup 1.0000x reference)
//
#include <hip/hip_runtime.h>
#include <math.h>

// Problem constants (from reference)
#define POOLD 50
#define GFD   45
#define DNND  400
#define ZIN   (POOLD + GFD)   // 95

// Parallel decomposition: 25 wgs x 16 output columns = 400 outputs/layer.
// t = kt*16 + tt ; tt = output col (16 consecutive -> one 64B line per
// K-row, perfect per-wg line ownership), kt = 32-way K-split over 8 waves.
// v10: ALL 6 mid-layers' weights (78 f/thread) issued+pinned in the
// PROLOGUE. v9's per-layer pin forced a serial ~0.7us s_waitcnt before
// every poll (a "+v" pin reads the register => compiler must wait the
// load). One ~2us drain up front replaces 6 serial waits; each layer's
// path is now poll-RT -> LDS stage -> 13 FMA -> reduce -> publish.
#define NWG 25
#define TT  16
#define KT  32
#define BLK 512               // 8 waves
#define NKF 12                // full k-iters; 13th only for kt<16

// Epoch-tagged exchange slots (v8 protocol): 8B (tag|value) pairs;
// persistent epoch counter read once, publishes tagged epoch+1, block 0
// advances the epoch after the final gather. Self-initializing under any
// workspace poison; no memset, single graph node.
#define EXU   512             // u64 slots per exchange buffer (4 KB)
#define NEX   6               // dnn0 out + mid0..mid4 out (mid5 is fused)

__device__ __forceinline__ float elu1(float x) {
    return x > 0.f ? x : expm1f(x);
}

// The entire GNN front-end is analytically dead:
//   global_mean_pool(BatchNorm_trainstats(h)) == bnpool_b  (exactly)
// so the output reduces to a tiny MLP on constants + gf1.
__global__ __launch_bounds__(BLK) void GATGraphModel_tail_v10(
    const float* __restrict__ gf1,        // [45]
    const float* __restrict__ bnpool_b,   // [14]
    const float* __restrict__ ugp1_W,     // [14,50]
    const float* __restrict__ ugp1_b,     // [50]
    const float* __restrict__ ugp2_W,     // [50,50]
    const float* __restrict__ ugp2_b,     // [50]
    const float* __restrict__ dnn0_W,     // [95,400]
    const float* __restrict__ dnn0_b,     // [400]
    const float* __restrict__ dnn_mid_W,  // [6,400,400]
    const float* __restrict__ dnn_mid_b,  // [6,400]
    const float* __restrict__ dnn_last_W, // [400,1]
    const float* __restrict__ dnn_last_b, // [1]
    float* __restrict__ out,              // [1]
    float* __restrict__ ws)               // 6*4KB exchanges + finsl + epoch
{
    __shared__ float zs[DNND];     // staged activation vector
    __shared__ float pr[128];      // 8 waves x 16 per-wave partials
    __shared__ float h2[POOLD];

    const int t     = threadIdx.x;
    const int tt    = t & (TT - 1);     // output col within wg's 16
    const int kt    = t >> 4;           // K-slice 0..31 (spans 8 waves)
    const int lane  = t & 63;
    const int wv    = t >> 6;           // wave 0..7
    const int tbase = blockIdx.x * TT;

    unsigned long long* exb    = (unsigned long long*)ws;  // 6 x 512 u64
    unsigned long long* finsl  = exb + (size_t)NEX * EXU;  // [25] tagged partials
    unsigned int*       epochp = (unsigned int*)(finsl + 32);

    // ---- epoch read (uniform; one RT, overlapped with the prologue)
    const unsigned int tag =
        __hip_atomic_load(epochp, __ATOMIC_RELAXED, __HIP_MEMORY_SCOPE_AGENT) + 1u;
    const unsigned long long tagw = (unsigned long long)tag << 32;

    // ---- issue dnn0 weight slice + last-layer weight, pin (small wait,
    // overlaps the epoch RT)
    float w0[3];
    #pragma unroll
    for (int j = 0; j < 3; ++j) {
        int k = kt + j * KT; if (k > ZIN - 1) k = ZIN - 1;  // clamp; guarded at use
        w0[j] = dnn0_W[k * DNND + tbase + tt];
    }
    float wlast = dnn_last_W[tbase + tt];   // fused-final weight
    #pragma unroll
    for (int j = 0; j < 3; ++j) asm volatile("" : "+v"(w0[j]));
    asm volatile("" : "+v"(wlast));

    // ---- ugp chain, redundantly in every wg (13 KB of cached reads —
    // cheaper than any exchange): p0 = bnpool_b ; h2 = p0@ugp1 + b
    if (t < POOLD) {
        float acc = ugp1_b[t];
        #pragma unroll
        for (int c = 0; c < 14; ++c) acc += bnpool_b[c] * ugp1_W[c * POOLD + t];
        h2[t] = acc;
    }
    __syncthreads();
    // p = h2 @ ugp2_W + b ; z = concat(p, gf1) -> zs[0:95]
    if (t < POOLD) {
        float acc = ugp2_b[t];
        #pragma unroll 10
        for (int k = 0; k < POOLD; ++k) acc += h2[k] * ugp2_W[k * POOLD + t];
        zs[t] = acc;
    } else if (t < ZIN) {
        zs[t] = gf1[t - POOLD];
    }
    __syncthreads();

    // ---- issue ALL 6 mid layers' weights + biases (78+6 loads/thread).
    // 153 KB/wg drains through 8 waves' outstanding-load capacity in ~2us,
    // ONCE, overlapped below with the dnn0 compute/publish/RT.
    float wm[6][13];
    float bm[6];
    #pragma unroll
    for (int i = 0; i < 6; ++i) {
        const float* __restrict__ W = dnn_mid_W + (size_t)i * DNND * DNND;
        #pragma unroll
        for (int j = 0; j < 13; ++j) {
            int k = kt + j * KT; if (k > DNND - 1) k = DNND - 1;  // clamp
            wm[i][j] = W[k * DNND + tbase + tt];
        }
        bm[i] = dnn_mid_b[i * DNND + tbase + tt];
    }

    // ---- dnn0: elu(z95 @ dnn0_W + b) -> exchange 0 (only needs w0)
    {
        float acc = zs[kt] * w0[0];                 // kt < 32 < 95 always
        acc += zs[kt + KT] * w0[1];                 // kt+32 < 64 < 95 always
        if (kt + 2 * KT < ZIN) acc += zs[kt + 2 * KT] * w0[2];
        acc += __shfl_down(acc, 32, 64);    // fold kt pairs across half-wave
        acc += __shfl_down(acc, 16, 64);
        if (lane < TT) pr[wv * TT + lane] = acc;
        __syncthreads();
        if (t < TT) {
            float v = pr[t];
            #pragma unroll
            for (int w = 1; w < 8; ++w) v += pr[w * TT + t];
            v = elu1(v + dnn0_b[tbase + t]);
            __hip_atomic_store(&exb[tbase + t], tagw | __float_as_uint(v),
                               __ATOMIC_RELAXED, __HIP_MEMORY_SCOPE_AGENT);
        }
    }

    // ---- pin the full weight set: ONE drain wait, overlapping the dnn0
    // exchange round-trip that the consumers must wait out anyway.
    #pragma unroll
    for (int i = 0; i < 6; ++i) {
        #pragma unroll
        for (int j = 0; j < 13; ++j) asm volatile("" : "+v"(wm[i][j]));
        asm volatile("" : "+v"(bm[i]));
    }

    // ---- 6 mid layers: z = elu(elu(z @ W + b)); layer i reads exchange i.
    // No VMEM waits left on this path: weights are already in VGPRs.
    #pragma unroll
    for (int i = 0; i < 6; ++i) {
        // poll the tagged 8B slots of exchange i -> zs (one slot/thread)
        const unsigned long long* s8 = exb + (size_t)i * EXU;
        if (t < DNND) {
            unsigned long long v;
            do {
                v = __hip_atomic_load(&s8[t], __ATOMIC_RELAXED,
                                      __HIP_MEMORY_SCOPE_AGENT);
            } while ((unsigned int)(v >> 32) != tag);
            zs[t] = __uint_as_float((unsigned int)v);
        }
        __syncthreads();   // barrier 1: zs staged

        float acc = 0.f;
        #pragma unroll
        for (int j = 0; j < NKF; ++j) acc += zs[kt + j * KT] * wm[i][j];
        if (kt < DNND - NKF * KT) acc += zs[kt + NKF * KT] * wm[i][12];
        acc += __shfl_down(acc, 32, 64);
        acc += __shfl_down(acc, 16, 64);
        if (lane < TT) pr[wv * TT + lane] = acc;
        __syncthreads();   // barrier 2: partials visible

        if (t < TT) {
            float v = pr[t];
            #pragma unroll
            for (int w = 1; w < 8; ++w) v += pr[w * TT + t];
            v = elu1(elu1(v + bm[i]));
            if (i < 5) {
                __hip_atomic_store(&exb[(size_t)(i + 1) * EXU + tbase + t],
                                   tagw | __float_as_uint(v),
                                   __ATOMIC_RELAXED, __HIP_MEMORY_SCOPE_AGENT);
            } else {
                // fused final dot: 16 outputs x dnn_last_W, shuffle-reduced
                float p = v * wlast;   // for t<16, wlast = dnn_last_W[tbase+t]
                p += __shfl_down(p, 8, 16);
                p += __shfl_down(p, 4, 16);
                p += __shfl_down(p, 2, 16);
                p += __shfl_down(p, 1, 16);
                if (t == 0)
                    __hip_atomic_store(&finsl[blockIdx.x],
                                       tagw | __float_as_uint(p),
                                       __ATOMIC_RELAXED,
                                       __HIP_MEMORY_SCOPE_AGENT);
            }
        }
    }

    // ---- wg0, wave 0: gather 25 tagged partials by shuffle, sigmoid
    if (blockIdx.x == 0 && wv == 0) {
        float p = 0.f;
        if (lane < NWG) {
            unsigned long long v;
            do {
                v = __hip_atomic_load(&finsl[lane], __ATOMIC_RELAXED,
                                      __HIP_MEMORY_SCOPE_AGENT);
            } while ((unsigned int)(v >> 32) != tag);
            p = __uint_as_float((unsigned int)v);
        }
        p += __shfl_down(p, 32, 64);
        p += __shfl_down(p, 16, 64);
        p += __shfl_down(p, 8, 64);
        p += __shfl_down(p, 4, 64);
        p += __shfl_down(p, 2, 64);
        p += __shfl_down(p, 1, 64);
        if (lane == 0) {
            float s = p + dnn_last_b[0];
            out[0] = 1.f / (1.f + expf(-s));
            // advance the epoch: reaching here proves all 25 blocks
            // published (=> all read the old epoch), so this is race-free.
            __hip_atomic_store(epochp, tag, __ATOMIC_RELAXED,
                               __HIP_MEMORY_SCOPE_AGENT);
        }
    }
}

extern "C" void kernel_launch(void* const* d_in, const int* in_sizes, int n_in,
                              void* d_out, int out_size, void* d_ws, size_t ws_size,
                              hipStream_t stream) {
    // setup_inputs() order:
    //  0 x, 1 edge_attr, 2 gf1, 3 bn_in_g, 4 bn_in_b,
    //  5 gat0_W, 6 gat0_asrc, 7 gat0_adst, 8 gat0_bias,
    //  9 gat_mid_W, 10 gat_mid_asrc, 11 gat_mid_adst, 12 gat_mid_bias,
    // 13 bn_mid_g, 14 bn_mid_b,
    // 15 gat_last_W, 16 gat_last_asrc, 17 gat_last_adst, 18 gat_last_bias,
    // 19 bnpool_g, 20 bnpool_b, 21 ugp1_W, 22 ugp1_b, 23 ugp2_W, 24 ugp2_b,
    // 25 dnn0_W, 26 dnn0_b, 27 dnn_mid_W, 28 dnn_mid_b, 29 dnn_last_W,
    // 30 dnn_last_b, 31 edge_index, 32 batch
    const float* gf1        = (const float*)d_in[2];
    const float* bnpool_b   = (const float*)d_in[20];
    const float* ugp1_W     = (const float*)d_in[21];
    const float* ugp1_b     = (const float*)d_in[22];
    const float* ugp2_W     = (const float*)d_in[23];
    const float* ugp2_b     = (const float*)d_in[24];
    const float* dnn0_W     = (const float*)d_in[25];
    const float* dnn0_b     = (const float*)d_in[26];
    const float* dnn_mid_W  = (const float*)d_in[27];
    const float* dnn_mid_b  = (const float*)d_in[28];
    const float* dnn_last_W = (const float*)d_in[29];
    const float* dnn_last_b = (const float*)d_in[30];
    float* out = (float*)d_out;
    float* ws  = (float*)d_ws;

    // No memset: the epoch-tag protocol is self-initializing under any
    // workspace poison (see kernel comment). Single graph node.
    hipLaunchKernelGGL(GATGraphModel_tail_v10, dim3(NWG), dim3(BLK), 0, stream,
                       gf1, bnpool_b, ugp1_W, ugp1_b, ugp2_W, ugp2_b,
                       dnn0_W, dnn0_b, dnn_mid_W, dnn_mid_b,
                       dnn_last_W, dnn_last_b, out, ws);
}

// Round 10
// 17.462 us; speedup vs baseline: 1.0366x; 1.0366x over previous
//
#include <hip/hip_runtime.h>
#include <math.h>

// Problem constants (from reference)
#define POOLD 50
#define GFD   45
#define DNND  400
#define ZIN   (POOLD + GFD)   // 95

// Parallel decomposition: 25 wgs x 16 output columns = 400 outputs/layer.
// t = kt*16 + tt ; tt = output col (16 consecutive -> one 64B line per
// K-row, perfect per-wg line ownership), kt = 32-way K-split over 8 waves.
// v11 == v9 (best measured: 17.36us). v10's hoist-all-weights regressed:
// vmcnt is IN-ORDER, so any poll load issued after weight loads implies a
// full weight drain before the poll's own result is consumable — v9's
// per-layer issue already overlaps that drain (~0.7us) with the producer
// round-trip (~0.6us) the poll must wait out anyway. Per-layer cost is
// max(drain, RT), already minimal. The remaining 17.4us decomposes as
// ~4-5us launch/replay + ~2.5us prologue + 6 x ~1.3us algorithmically
// serial layers + ~0.7us gather: a latency floor, not BW or compute.
#define NWG 25
#define TT  16
#define KT  32
#define BLK 512               // 8 waves
#define NKF 12                // full k-iters; 13th only for kt<16

// Epoch-tagged exchange slots (v8 protocol): 8B (tag|value) pairs;
// persistent epoch counter read once, publishes tagged epoch+1, block 0
// advances the epoch after the final gather. Self-initializing under any
// workspace poison; no memset, single graph node.
#define EXU   512             // u64 slots per exchange buffer (4 KB)
#define NEX   6               // dnn0 out + mid0..mid4 out (mid5 is fused)

__device__ __forceinline__ float elu1(float x) {
    return x > 0.f ? x : expm1f(x);
}

// The entire GNN front-end is analytically dead:
//   global_mean_pool(BatchNorm_trainstats(h)) == bnpool_b  (exactly)
// so the output reduces to a tiny MLP on constants + gf1.
__global__ __launch_bounds__(BLK) void GATGraphModel_tail_v11(
    const float* __restrict__ gf1,        // [45]
    const float* __restrict__ bnpool_b,   // [14]
    const float* __restrict__ ugp1_W,     // [14,50]
    const float* __restrict__ ugp1_b,     // [50]
    const float* __restrict__ ugp2_W,     // [50,50]
    const float* __restrict__ ugp2_b,     // [50]
    const float* __restrict__ dnn0_W,     // [95,400]
    const float* __restrict__ dnn0_b,     // [400]
    const float* __restrict__ dnn_mid_W,  // [6,400,400]
    const float* __restrict__ dnn_mid_b,  // [6,400]
    const float* __restrict__ dnn_last_W, // [400,1]
    const float* __restrict__ dnn_last_b, // [1]
    float* __restrict__ out,              // [1]
    float* __restrict__ ws)               // 6*4KB exchanges + finsl + epoch
{
    __shared__ float zs[DNND];     // staged activation vector
    __shared__ float pr[128];      // 8 waves x 16 per-wave partials
    __shared__ float h2[POOLD];

    const int t     = threadIdx.x;
    const int tt    = t & (TT - 1);     // output col within wg's 16
    const int kt    = t >> 4;           // K-slice 0..31 (spans 8 waves)
    const int lane  = t & 63;
    const int wv    = t >> 6;           // wave 0..7
    const int tbase = blockIdx.x * TT;

    unsigned long long* exb    = (unsigned long long*)ws;  // 6 x 512 u64
    unsigned long long* finsl  = exb + (size_t)NEX * EXU;  // [25] tagged partials
    unsigned int*       epochp = (unsigned int*)(finsl + 32);

    // ---- epoch read (uniform; one RT, overlapped with the prologue)
    const unsigned int tag =
        __hip_atomic_load(epochp, __ATOMIC_RELAXED, __HIP_MEMORY_SCOPE_AGENT) + 1u;
    const unsigned long long tagw = (unsigned long long)tag << 32;

    // ---- preload dnn0 weight slice FIRST (overlaps the ugp dependent chain)
    float w0[3];
    #pragma unroll
    for (int j = 0; j < 3; ++j) {
        int k = kt + j * KT; if (k > ZIN - 1) k = ZIN - 1;  // clamp; guarded at use
        w0[j] = dnn0_W[k * DNND + tbase + tt];
    }
    #pragma unroll
    for (int j = 0; j < 3; ++j) asm volatile("" : "+v"(w0[j]));
    const float wlast = dnn_last_W[tbase + tt];   // fused-final weight

    // ---- ugp chain, redundantly in every wg (13 KB of cached reads —
    // cheaper than any exchange): p0 = bnpool_b ; h2 = p0@ugp1 + b
    if (t < POOLD) {
        float acc = ugp1_b[t];
        #pragma unroll
        for (int c = 0; c < 14; ++c) acc += bnpool_b[c] * ugp1_W[c * POOLD + t];
        h2[t] = acc;
    }
    __syncthreads();
    // p = h2 @ ugp2_W + b ; z = concat(p, gf1) -> zs[0:95]
    if (t < POOLD) {
        float acc = ugp2_b[t];
        #pragma unroll 10
        for (int k = 0; k < POOLD; ++k) acc += h2[k] * ugp2_W[k * POOLD + t];
        zs[t] = acc;
    } else if (t < ZIN) {
        zs[t] = gf1[t - POOLD];
    }
    __syncthreads();

    // ---- dnn0: elu(z95 @ dnn0_W + b) -> exchange 0
    {
        float acc = zs[kt] * w0[0];                 // kt < 32 < 95 always
        acc += zs[kt + KT] * w0[1];                 // kt+32 < 64 < 95 always
        if (kt + 2 * KT < ZIN) acc += zs[kt + 2 * KT] * w0[2];
        acc += __shfl_down(acc, 32, 64);    // fold kt pairs across half-wave
        acc += __shfl_down(acc, 16, 64);
        if (lane < TT) pr[wv * TT + lane] = acc;
        __syncthreads();
        if (t < TT) {
            float v = pr[t];
            #pragma unroll
            for (int w = 1; w < 8; ++w) v += pr[w * TT + t];
            v = elu1(v + dnn0_b[tbase + t]);
            __hip_atomic_store(&exb[tbase + t], tagw | __float_as_uint(v),
                               __ATOMIC_RELAXED, __HIP_MEMORY_SCOPE_AGENT);
        }
    }

    // ---- 6 mid layers: z = elu(elu(z @ W + b)); layer i reads exchange i
    for (int i = 0; i < 6; ++i) {
        const float* __restrict__ W = dnn_mid_W + (size_t)i * DNND * DNND;

        // preload this thread's 13 weight elems + bias; pin in VGPRs.
        // The pin's implied s_waitcnt drain (~0.7us) runs concurrently with
        // the producer round-trip (~0.6us) the poll below must wait out —
        // per-layer cost is max(drain, RT). Per instruction a wave touches
        // 4 K-rows x 16 consecutive floats = 4 full 64B lines.
        float w[13];
        #pragma unroll
        for (int j = 0; j < 13; ++j) {
            int k = kt + j * KT; if (k > DNND - 1) k = DNND - 1;  // clamp
            w[j] = W[k * DNND + tbase + tt];
        }
        float bmid = dnn_mid_b[i * DNND + tbase + tt];
        #pragma unroll
        for (int j = 0; j < 13; ++j) asm volatile("" : "+v"(w[j]));
        asm volatile("" : "+v"(bmid));

        // poll the tagged 8B slots of exchange i -> zs (one slot/thread)
        const unsigned long long* s8 = exb + (size_t)i * EXU;
        if (t < DNND) {
            unsigned long long v;
            do {
                v = __hip_atomic_load(&s8[t], __ATOMIC_RELAXED,
                                      __HIP_MEMORY_SCOPE_AGENT);
            } while ((unsigned int)(v >> 32) != tag);
            zs[t] = __uint_as_float((unsigned int)v);
        }
        __syncthreads();   // barrier 1: zs staged

        float acc = 0.f;
        #pragma unroll
        for (int j = 0; j < NKF; ++j) acc += zs[kt + j * KT] * w[j];
        if (kt < DNND - NKF * KT) acc += zs[kt + NKF * KT] * w[12];
        acc += __shfl_down(acc, 32, 64);
        acc += __shfl_down(acc, 16, 64);
        if (lane < TT) pr[wv * TT + lane] = acc;
        __syncthreads();   // barrier 2: partials visible

        if (t < TT) {
            float v = pr[t];
            #pragma unroll
            for (int w = 1; w < 8; ++w) v += pr[w * TT + t];
            v = elu1(elu1(v + bmid));
            if (i < 5) {
                __hip_atomic_store(&exb[(size_t)(i + 1) * EXU + tbase + t],
                                   tagw | __float_as_uint(v),
                                   __ATOMIC_RELAXED, __HIP_MEMORY_SCOPE_AGENT);
            } else {
                // fused final dot: 16 outputs x dnn_last_W, shuffle-reduced
                float p = v * wlast;   // for t<16, wlast = dnn_last_W[tbase+t]
                p += __shfl_down(p, 8, 16);
                p += __shfl_down(p, 4, 16);
                p += __shfl_down(p, 2, 16);
                p += __shfl_down(p, 1, 16);
                if (t == 0)
                    __hip_atomic_store(&finsl[blockIdx.x],
                                       tagw | __float_as_uint(p),
                                       __ATOMIC_RELAXED,
                                       __HIP_MEMORY_SCOPE_AGENT);
            }
        }
    }

    // ---- wg0, wave 0: gather 25 tagged partials by shuffle, sigmoid
    if (blockIdx.x == 0 && wv == 0) {
        float p = 0.f;
        if (lane < NWG) {
            unsigned long long v;
            do {
                v = __hip_atomic_load(&finsl[lane], __ATOMIC_RELAXED,
                                      __HIP_MEMORY_SCOPE_AGENT);
            } while ((unsigned int)(v >> 32) != tag);
            p = __uint_as_float((unsigned int)v);
        }
        p += __shfl_down(p, 32, 64);
        p += __shfl_down(p, 16, 64);
        p += __shfl_down(p, 8, 64);
        p += __shfl_down(p, 4, 64);
        p += __shfl_down(p, 2, 64);
        p += __shfl_down(p, 1, 64);
        if (lane == 0) {
            float s = p + dnn_last_b[0];
            out[0] = 1.f / (1.f + expf(-s));
            // advance the epoch: reaching here proves all 25 blocks
            // published (=> all read the old epoch), so this is race-free.
            __hip_atomic_store(epochp, tag, __ATOMIC_RELAXED,
                               __HIP_MEMORY_SCOPE_AGENT);
        }
    }
}

extern "C" void kernel_launch(void* const* d_in, const int* in_sizes, int n_in,
                              void* d_out, int out_size, void* d_ws, size_t ws_size,
                              hipStream_t stream) {
    // setup_inputs() order:
    //  0 x, 1 edge_attr, 2 gf1, 3 bn_in_g, 4 bn_in_b,
    //  5 gat0_W, 6 gat0_asrc, 7 gat0_adst, 8 gat0_bias,
    //  9 gat_mid_W, 10 gat_mid_asrc, 11 gat_mid_adst, 12 gat_mid_bias,
    // 13 bn_mid_g, 14 bn_mid_b,
    // 15 gat_last_W, 16 gat_last_asrc, 17 gat_last_adst, 18 gat_last_bias,
    // 19 bnpool_g, 20 bnpool_b, 21 ugp1_W, 22 ugp1_b, 23 ugp2_W, 24 ugp2_b,
    // 25 dnn0_W, 26 dnn0_b, 27 dnn_mid_W, 28 dnn_mid_b, 29 dnn_last_W,
    // 30 dnn_last_b, 31 edge_index, 32 batch
    const float* gf1        = (const float*)d_in[2];
    const float* bnpool_b   = (const float*)d_in[20];
    const float* ugp1_W     = (const float*)d_in[21];
    const float* ugp1_b     = (const float*)d_in[22];
    const float* ugp2_W     = (const float*)d_in[23];
    const float* ugp2_b     = (const float*)d_in[24];
    const float* dnn0_W     = (const float*)d_in[25];
    const float* dnn0_b     = (const float*)d_in[26];
    const float* dnn_mid_W  = (const float*)d_in[27];
    const float* dnn_mid_b  = (const float*)d_in[28];
    const float* dnn_last_W = (const float*)d_in[29];
    const float* dnn_last_b = (const float*)d_in[30];
    float* out = (float*)d_out;
    float* ws  = (float*)d_ws;

    // No memset: the epoch-tag protocol is self-initializing under any
    // workspace poison (see kernel comment). Single graph node.
    hipLaunchKernelGGL(GATGraphModel_tail_v11, dim3(NWG), dim3(BLK), 0, stream,
                       gf1, bnpool_b, ugp1_W, ugp1_b, ugp2_W, ugp2_b,
                       dnn0_W, dnn0_b, dnn_mid_W, dnn_mid_b,
                       dnn_last_W, dnn_last_b, out, ws);
}